// Round 1
// baseline (162.331 us; speedup 1.0000x reference)
//
#include <hip/hip_runtime.h>

// Problem: BATCH=64, NFILT=512, T=1024, FFT over first 512 samples, 257 bins.
//   bc = (fc/Q)*0.5*sqrt(2pi)/FS ; n = t+1
//   y[b,f,t] = exp(-(bc*n)^2) * cos(2pi*fc/FS*n)
//   maxsq[f] = max_{b,k} |DFT_512(y[b,f,0:512])[k]|^2
//   out[b,f,t] = y[b,f,1023-t] * rsqrt(maxsq[f])
//
// R10 = exact R6 (best known, 164.7us) + Q-candidate pruning ONLY.
//   Pruning: all b of a filter share kc => same fractional bin offset.
//   Peak-bin value v(bc) is strictly decreasing in bc for bc > 0.00434,
//   so the batch max lives in {bc <= 1.3*bc_min}; competitors >= 20% down.
//   Filters with fc < 700 Hz evaluate all 64 (non-monotone corner).
//   Surviving waves are bit-identical to R6 => absmax unchanged.
//
// R11 (this round): bit-identical resubmission — previous bench failed with
// GPUAcquisitionTimeout (no counters). Re-measure to split dur between
// k_maxfft and k_write before structural edits.

#define BCOEF_K 7.8332133582218756e-05f  // 0.5*sqrt(2*pi)/16000
#define INV_FS  6.25e-05f                // 1/16000
#define TWO_PI  6.28318530717958647692f
#define PI_F    3.14159265358979323846f
#define SIGK_K  115.2309f                // sqrt(2)*512/(2*pi)
#define KAPPA   1.3f                     // pruning safety factor
#define FULL_FC 700.0f                   // below this fc, evaluate all 64 b

typedef float vf4 __attribute__((ext_vector_type(4)));  // nt-store compatible

// cos(2*pi * n * fcn), phase reduced in revolutions -> native v_cos.
__device__ __forceinline__ float fast_carrier(float fcn, float n) {
  float rev = fcn * n;
  float fr  = rev - floorf(rev);
  return __cosf(TWO_PI * fr);
}
__device__ __forceinline__ float fast_env(float x) { return __expf(-x * x); }

// ---------------------------------------------------------------------------
// Kernel 1: block = 4 independent waves; wave w owns signal sig = blk*4+w.
// Wave generates its truncated signal into its private LDS row (lane-strided),
// then one windowed Goertzel pass. Result -> ws[f*64 + bb]. No barriers.
// ---------------------------------------------------------------------------
__global__ __launch_bounds__(256) void k_maxfft(const float* __restrict__ Q,
                                                const float* __restrict__ fc,
                                                float* __restrict__ ws) {
  const int tid  = threadIdx.x;
  const int w    = tid >> 6;           // wave 0..3
  const int lane = tid & 63;
  const int sig  = blockIdx.x * 4 + w; // bb*512 + f
  const int f    = sig & 511;
  const int bb   = sig >> 9;

  __shared__ __align__(16) float ybuf[4][512];

  const float fcv = fc[f];
  const float q   = Q[bb * 512 + f];
  const float bc  = (fcv / q) * BCOEF_K;
  const float fcn = fcv * INV_FS;

  // --- pruning: candidate iff bc <= KAPPA * bc_min(batch) or low-fc ---
  float qq = Q[lane * 512 + f];        // lane = batch index (Q is L2-hot)
  #pragma unroll
  for (int d = 32; d > 0; d >>= 1) qq = fmaxf(qq, __shfl_xor(qq, d));
  if (fcv >= FULL_FC && bc * qq > KAPPA * fcv * BCOEF_K) {
    if (lane == 0) ws[f * 64 + bb] = 0.0f;   // provably below batch max
    return;                                   // wave-uniform exit
  }

  // --- effective length: env < e^-16 beyond nstar = 4/bc (wave-uniform) ---
  const float nstar = 4.0f / bc;
  const int   N_eff = (nstar >= 510.0f) ? 512 : ((int)nstar + 2);
  const int   jmax  = (N_eff + 3) >> 2;      // float4 groups Goertzel reads
  const int   n4    = jmax << 2;             // samples to generate

  // --- lane-strided generation: lane writes samples lane, lane+64, ... ---
  float* yw = &ybuf[w][0];
  const int nit_g = (n4 + 63) >> 6;          // 1..8, wave-uniform
  for (int r = 0; r < nit_g; ++r) {
    const int idx = (r << 6) + lane;         // t index; n = idx+1
    const float n = (float)(idx + 1);
    const float v = fast_env(bc * n) * fast_carrier(fcn, n);
    if (idx < n4) yw[idx] = v;               // masked tail store
  }
  // Wave-local write->read ordering (row is private to this wave).
  asm volatile("s_waitcnt lgkmcnt(0)" ::: "memory");

  // --- spectral-peak window (wave-uniform) ---
  const int kci  = (int)(fcn * 512.0f + 0.5f);
  const int W    = (int)(2.0f * (bc * SIGK_K)) + 6;
  const int k_lo = max(0, kci - W);
  const int k_hi = min(256, kci + W);
  const int nit  = ((k_hi - k_lo) >> 6) + 1;  // 1..5 iterations

  const float4* y4 = (const float4*)yw;      // wave-uniform broadcasts
  float mx = 0.0f;
  for (int it = 0; it < nit; ++it) {         // wave-uniform trip count
    const int   k = min(k_lo + (it << 6) + lane, k_hi);  // dup bins harmless
    const float c = 2.0f * cosf((float)k * (PI_F / 256.0f));
    float s1 = 0.0f, s2 = 0.0f;
    #pragma unroll 4
    for (int j = 0; j < jmax; ++j) {         // wave-uniform trip count
      const float4 x = y4[j];
      float s;
      s = fmaf(c, s1, x.x - s2); s2 = s1; s1 = s;
      s = fmaf(c, s1, x.y - s2); s2 = s1; s1 = s;
      s = fmaf(c, s1, x.z - s2); s2 = s1; s1 = s;
      s = fmaf(c, s1, x.w - s2); s2 = s1; s1 = s;
    }
    mx = fmaxf(mx, fmaf(s1, s1, fmaf(s2, s2, -(c * s1 * s2))));
  }

  #pragma unroll
  for (int d = 32; d > 0; d >>= 1) mx = fmaxf(mx, __shfl_xor(mx, d));
  if (lane == 0) ws[f * 64 + bb] = mx;       // per-signal result, no atomic
}

// ---------------------------------------------------------------------------
// Kernel 2: one block per (b,f) row. Wave loads the 64 per-batch results for
// f (pruned entries are 0.0, harmless under max), shfl-max; thread tid writes
// float4 at t0=4*tid, n = 1024 - t (flip), scaled by rsqrt(maxsq).
// Dead tail stores zeros. Nontemporal streaming stores. (Exact R6 k_write.)
// ---------------------------------------------------------------------------
__global__ __launch_bounds__(256) void k_write(const float* __restrict__ Q,
                                               const float* __restrict__ fc,
                                               const float* __restrict__ ws,
                                               float* __restrict__ out) {
  const int blk = blockIdx.x;      // bb*512 + f
  const int f   = blk & 511;
  const int bb  = blk >> 9;
  const int tid = threadIdx.x;

  float mx = ws[f * 64 + (tid & 63)];
  #pragma unroll
  for (int d = 32; d > 0; d >>= 1) mx = fmaxf(mx, __shfl_xor(mx, d));

  const float fcv = fc[f];
  const float q   = Q[bb * 512 + f];
  const float bc  = (fcv / q) * BCOEF_K;
  const float fcn = fcv * INV_FS;
  const float nstar = 4.0f / bc;

  const int t0 = tid * 4;
  vf4 r = {0.0f, 0.0f, 0.0f, 0.0f};
  // quad covers n = 1021-t0 .. 1024-t0; all dead iff smallest n > nstar
  if ((float)(1021 - t0) <= nstar) {
    const float inv = rsqrtf(mx);
    const float n0 = (float)(1024 - t0);
    const float n1 = (float)(1023 - t0);
    const float n2 = (float)(1022 - t0);
    const float n3 = (float)(1021 - t0);
    r.x = fast_env(bc * n0) * fast_carrier(fcn, n0) * inv;
    r.y = fast_env(bc * n1) * fast_carrier(fcn, n1) * inv;
    r.z = fast_env(bc * n2) * fast_carrier(fcn, n2) * inv;
    r.w = fast_env(bc * n3) * fast_carrier(fcn, n3) * inv;
  }
  __builtin_nontemporal_store(r, &((vf4*)out)[blk * 256 + tid]);
}

// ---------------------------------------------------------------------------
extern "C" void kernel_launch(void* const* d_in, const int* in_sizes, int n_in,
                              void* d_out, int out_size, void* d_ws, size_t ws_size,
                              hipStream_t stream) {
  const float* Q  = (const float*)d_in[0];   // [64, 512] f32
  const float* fc = (const float*)d_in[1];   // [512] f32
  float* out      = (float*)d_out;           // [64, 512, 1024] f32
  float* ws       = (float*)d_ws;            // [512*64] per-signal |X|^2 max

  k_maxfft<<<64 * 512 / 4, 256, 0, stream>>>(Q, fc, ws);
  k_write <<<64 * 512,     256, 0, stream>>>(Q, fc, ws, out);
}

// Round 2
// 159.418 us; speedup vs baseline: 1.0183x; 1.0183x over previous
//
#include <hip/hip_runtime.h>

// Problem: BATCH=64, NFILT=512, T=1024, FFT over first 512 samples, 257 bins.
//   bc = (fc/Q)*0.5*sqrt(2pi)/FS ; n = t+1
//   y[b,f,t] = exp(-(bc*n)^2) * cos(2pi*fc/FS*n)
//   maxsq[f] = max_{b,k} |DFT_512(y[b,f,0:512])[k]|^2
//   out[b,f,t] = y[b,f,1023-t] * rsqrt(maxsq[f])
//
// R12 (this round): k_maxfft BYTE-IDENTICAL to R10/R11 (162.3us measured).
//   k_write rewritten:  (a) plain cached stores instead of nontemporal
//   (fillBuffer proves 6.2 TB/s with cached streaming stores), (b) one wave
//   per output row (4 rows/block, 8192 blocks instead of 32768), one
//   ws-reduce per row instead of four, 4 quads per lane. Timing delta vs
//   R11 attributes entirely to k_write (k_maxfft untouched).
//   Floor: 128 MiB stores / 6.2 TB/s ~= 22 us. Predicted total ~105 us.

#define BCOEF_K 7.8332133582218756e-05f  // 0.5*sqrt(2*pi)/16000
#define INV_FS  6.25e-05f                // 1/16000
#define TWO_PI  6.28318530717958647692f
#define PI_F    3.14159265358979323846f
#define SIGK_K  115.2309f                // sqrt(2)*512/(2*pi)
#define KAPPA   1.3f                     // pruning safety factor
#define FULL_FC 700.0f                   // below this fc, evaluate all 64 b

typedef float vf4 __attribute__((ext_vector_type(4)));

// cos(2*pi * n * fcn), phase reduced in revolutions -> native v_cos.
__device__ __forceinline__ float fast_carrier(float fcn, float n) {
  float rev = fcn * n;
  float fr  = rev - floorf(rev);
  return __cosf(TWO_PI * fr);
}
__device__ __forceinline__ float fast_env(float x) { return __expf(-x * x); }

// ---------------------------------------------------------------------------
// Kernel 1: block = 4 independent waves; wave w owns signal sig = blk*4+w.
// Wave generates its truncated signal into its private LDS row (lane-strided),
// then one windowed Goertzel pass. Result -> ws[f*64 + bb]. No barriers.
// (BYTE-IDENTICAL to R10/R11 — do not touch; timing attribution anchor.)
// ---------------------------------------------------------------------------
__global__ __launch_bounds__(256) void k_maxfft(const float* __restrict__ Q,
                                                const float* __restrict__ fc,
                                                float* __restrict__ ws) {
  const int tid  = threadIdx.x;
  const int w    = tid >> 6;           // wave 0..3
  const int lane = tid & 63;
  const int sig  = blockIdx.x * 4 + w; // bb*512 + f
  const int f    = sig & 511;
  const int bb   = sig >> 9;

  __shared__ __align__(16) float ybuf[4][512];

  const float fcv = fc[f];
  const float q   = Q[bb * 512 + f];
  const float bc  = (fcv / q) * BCOEF_K;
  const float fcn = fcv * INV_FS;

  // --- pruning: candidate iff bc <= KAPPA * bc_min(batch) or low-fc ---
  float qq = Q[lane * 512 + f];        // lane = batch index (Q is L2-hot)
  #pragma unroll
  for (int d = 32; d > 0; d >>= 1) qq = fmaxf(qq, __shfl_xor(qq, d));
  if (fcv >= FULL_FC && bc * qq > KAPPA * fcv * BCOEF_K) {
    if (lane == 0) ws[f * 64 + bb] = 0.0f;   // provably below batch max
    return;                                   // wave-uniform exit
  }

  // --- effective length: env < e^-16 beyond nstar = 4/bc (wave-uniform) ---
  const float nstar = 4.0f / bc;
  const int   N_eff = (nstar >= 510.0f) ? 512 : ((int)nstar + 2);
  const int   jmax  = (N_eff + 3) >> 2;      // float4 groups Goertzel reads
  const int   n4    = jmax << 2;             // samples to generate

  // --- lane-strided generation: lane writes samples lane, lane+64, ... ---
  float* yw = &ybuf[w][0];
  const int nit_g = (n4 + 63) >> 6;          // 1..8, wave-uniform
  for (int r = 0; r < nit_g; ++r) {
    const int idx = (r << 6) + lane;         // t index; n = idx+1
    const float n = (float)(idx + 1);
    const float v = fast_env(bc * n) * fast_carrier(fcn, n);
    if (idx < n4) yw[idx] = v;               // masked tail store
  }
  // Wave-local write->read ordering (row is private to this wave).
  asm volatile("s_waitcnt lgkmcnt(0)" ::: "memory");

  // --- spectral-peak window (wave-uniform) ---
  const int kci  = (int)(fcn * 512.0f + 0.5f);
  const int W    = (int)(2.0f * (bc * SIGK_K)) + 6;
  const int k_lo = max(0, kci - W);
  const int k_hi = min(256, kci + W);
  const int nit  = ((k_hi - k_lo) >> 6) + 1;  // 1..5 iterations

  const float4* y4 = (const float4*)yw;      // wave-uniform broadcasts
  float mx = 0.0f;
  for (int it = 0; it < nit; ++it) {         // wave-uniform trip count
    const int   k = min(k_lo + (it << 6) + lane, k_hi);  // dup bins harmless
    const float c = 2.0f * cosf((float)k * (PI_F / 256.0f));
    float s1 = 0.0f, s2 = 0.0f;
    #pragma unroll 4
    for (int j = 0; j < jmax; ++j) {         // wave-uniform trip count
      const float4 x = y4[j];
      float s;
      s = fmaf(c, s1, x.x - s2); s2 = s1; s1 = s;
      s = fmaf(c, s1, x.y - s2); s2 = s1; s1 = s;
      s = fmaf(c, s1, x.z - s2); s2 = s1; s1 = s;
      s = fmaf(c, s1, x.w - s2); s2 = s1; s1 = s;
    }
    mx = fmaxf(mx, fmaf(s1, s1, fmaf(s2, s2, -(c * s1 * s2))));
  }

  #pragma unroll
  for (int d = 32; d > 0; d >>= 1) mx = fmaxf(mx, __shfl_xor(mx, d));
  if (lane == 0) ws[f * 64 + bb] = mx;       // per-signal result, no atomic
}

// ---------------------------------------------------------------------------
// Kernel 2 (R12 rewrite): one WAVE per (b,f) output row; 4 rows per block;
// grid 8192. Wave loads the 64 per-batch results for f (coalesced, L2-hot),
// shfl-max ONCE, then stores 4x float4 per lane (4 KB contiguous per wave
// per step). Plain cached stores — no nontemporal.
// ---------------------------------------------------------------------------
__global__ __launch_bounds__(256) void k_write(const float* __restrict__ Q,
                                               const float* __restrict__ fc,
                                               const float* __restrict__ ws,
                                               float* __restrict__ out) {
  const int tid  = threadIdx.x;
  const int w    = tid >> 6;            // wave = row within the 4-row block
  const int lane = tid & 63;
  const int sig  = blockIdx.x * 4 + w;  // bb*512 + f
  const int f    = sig & 511;
  const int bb   = sig >> 9;

  float mx = ws[f * 64 + lane];         // 64 consecutive floats, coalesced
  #pragma unroll
  for (int d = 32; d > 0; d >>= 1) mx = fmaxf(mx, __shfl_xor(mx, d));
  const float inv = rsqrtf(mx);

  const float fcv = fc[f];
  const float q   = Q[bb * 512 + f];
  const float bc  = (fcv / q) * BCOEF_K;
  const float fcn = fcv * INV_FS;
  const float nstar = 4.0f / bc;

  vf4* __restrict__ orow = (vf4*)out + (size_t)sig * 256;
  #pragma unroll
  for (int r = 0; r < 4; ++r) {
    const int qi = (r << 6) + lane;     // quad index within row, 0..255
    const int t0 = qi << 2;             // t of first element in quad
    vf4 v = {0.0f, 0.0f, 0.0f, 0.0f};
    // quad covers n = 1021-t0 .. 1024-t0; all dead iff smallest n > nstar
    if ((float)(1021 - t0) <= nstar) {
      const float n0 = (float)(1024 - t0);
      const float n1 = (float)(1023 - t0);
      const float n2 = (float)(1022 - t0);
      const float n3 = (float)(1021 - t0);
      v.x = fast_env(bc * n0) * fast_carrier(fcn, n0) * inv;
      v.y = fast_env(bc * n1) * fast_carrier(fcn, n1) * inv;
      v.z = fast_env(bc * n2) * fast_carrier(fcn, n2) * inv;
      v.w = fast_env(bc * n3) * fast_carrier(fcn, n3) * inv;
    }
    orow[qi] = v;                       // plain cached store, coalesced 4KB/wave
  }
}

// ---------------------------------------------------------------------------
extern "C" void kernel_launch(void* const* d_in, const int* in_sizes, int n_in,
                              void* d_out, int out_size, void* d_ws, size_t ws_size,
                              hipStream_t stream) {
  const float* Q  = (const float*)d_in[0];   // [64, 512] f32
  const float* fc = (const float*)d_in[1];   // [512] f32
  float* out      = (float*)d_out;           // [64, 512, 1024] f32
  float* ws       = (float*)d_ws;            // [512*64] per-signal |X|^2 max

  k_maxfft<<<64 * 512 / 4, 256, 0, stream>>>(Q, fc, ws);
  k_write <<<64 * 512 / 4, 256, 0, stream>>>(Q, fc, ws, out);
}